// Round 6
// baseline (109.535 us; speedup 1.0000x reference)
//
#include <hip/hip_runtime.h>

typedef __bf16 bf16;
typedef __attribute__((ext_vector_type(8))) bf16 bf16x8;
typedef __attribute__((ext_vector_type(4))) float f32x4;

namespace {

constexpr int NITERS = 50;   // R11 ERRATUM: ref's 50-iter iterate is NOT the
                             // fixed point; count must match exactly.
constexpr int KEXACT = 16;   // updates 0..15 use exact v_rcp (trans pipe);
                             // 16..49 use one Newton step.

// ---- compile-time physical constants (double) ----
constexpr double csqrt(double x) {
  double s = x > 1 ? x : 1;
  for (int i = 0; i < 60; ++i) s = 0.5 * (s + x / s);
  return s;
}
constexpr double AP_D =
    ((3.667 - 1.0) / (3.667 + 0.5)) * (0.3 * (7.5 * csqrt(7.5)) / 0.0002395);
constexpr double RGAST_D = (8.3144598 / 4184.0) * 623.15;

__device__ __forceinline__ float sss_val(int i, int j) {
  // SSS[i][j] = exp(-DELTAW/(RGAS*T)); symmetric; zero outside 51x51 (pad)
  if (i > 50 || j > 50) return 0.0f;
  const float si = -0.025f + 0.001f * (float)i;
  const float sj = -0.025f + 0.001f * (float)j;
  const float acc = fmaxf(0.0f, fmaxf(si, sj) - 0.0084f);
  const float don = fminf(0.0f, fminf(si, sj) + 0.0084f);
  const float dw = (float)(AP_D * 0.5) * (si + sj) * (si + sj) + 85580.0f * acc * don;
  return expf(-dw * (float)(1.0 / RGAST_D));
}

// Row-slot -> actual sigma-row. Slots 0..47 = rows 0..47. The 3 remaining
// real rows (48,49,50) live in tile-3 class r=0 (slots 48,52,56 = g 0..2);
// ALL of classes (tp=3, r>=1) are pad.
__device__ __forceinline__ int slot2row(int slot) {
  if (slot < 48) return slot;
  if ((slot & 3) == 0 && slot < 60) return 48 + ((slot - 48) >> 2);
  return 99;   // pad -> sss_val 0 / load 0
}

__device__ __forceinline__ float fast_log(float x) {
  return __builtin_amdgcn_logf(x) * 0.69314718056f;   // ln via log2
}

// HW-verified gfx950 shape (guide §3; R4/R5/R8/R9 passed with it).
__device__ __forceinline__ f32x4 mfma(bf16x8 a, bf16x8 b, f32x4 c) {
  return __builtin_amdgcn_mfma_f32_16x16x32_bf16(a, b, c, 0, 0, 0);
}

// Packed f32->bf16 (RNE, same rounding as the cast). Guide T12: no builtin
// on gfx950 — inline asm. Non-volatile: pure value op, let the scheduler
// move/CSE it. One instruction produces one packed dword of the B-fragment.
__device__ __forceinline__ unsigned cvt_pk(float lo, float hi) {
  unsigned r;
  asm("v_cvt_pk_bf16_f32 %0, %1, %2" : "=v"(r) : "v"(lo), "v"(hi));
  return r;
}

union B8 { unsigned u[4]; bf16x8 v; };

} // namespace

// One wave = ONE chain of 16 solves (8 elements x {pure,mix}); grid B/32,
// 4 waves/SIMD. R6: B-fragment build via 7 inline-asm v_cvt_pk_bf16_f32
// (replaces 13 scalar casts + packing — the cvt chain sits on the
// acc->MFMA dependency path); scalar float arrays for all state (no
// vector-wrapper extract/insert); s_setprio(1) around the MFMA cluster.
__global__ __launch_bounds__(256, 4) void cosmo_mfma_r6(
    const float* __restrict__ my_sigma,   // [B,51]
    const float* __restrict__ v_comp,     // [B]
    const float* __restrict__ vt_sigma,   // [B,51,2]
    const float* __restrict__ v_vt,       // [B]
    float* __restrict__ out,              // [B]
    int B)
{
  const int lane = threadIdx.x & 63;
  const int wv   = threadIdx.x >> 6;
  const int s    = lane & 15;     // solve slot (C col / A-frag m pos)
  const int g    = lane >> 4;     // lane group 0..3
  const int task = s & 1;         // 0 = pure, 1 = mix
  const int e    = blockIdx.x * 32 + wv * 8 + (s >> 1);
  const bool ein = (e < B);
  const int  ec  = ein ? e : 0;

  // ---- prologue: rows owned by this lane (slot = 16t+4g+r) ----
  float A0, A1;
  float wh[13], Gt[13], rc[13];   // 12 live elements tiles 0-2, + 1 (tile3,r0)
  {
    float myv[13], vtv[13];
#pragma unroll
    for (int t = 0; t < 4; ++t)
#pragma unroll
      for (int r = 0; r < 4; ++r) {
        const int li = 4 * t + r;
        if (li >= 13) continue;                  // tile3 r>=1: dead
        const int n  = slot2row(16 * t + 4 * g + r);
        const bool nv = (n < 51) && ein;
        const int nc = (n < 51) ? n : 50;
        myv[li] = nv ? my_sigma[(size_t)ec * 51 + nc] : 0.0f;
        vtv[li] = nv ? vt_sigma[((size_t)ec * 51 + nc) * 2 + 1] : 0.0f;
      }
    float pA0 = 0.f, pA1 = 0.f;
#pragma unroll
    for (int i = 0; i < 13; ++i) { pA0 += myv[i]; pA1 += vtv[i]; }
    pA0 += __shfl_xor(pA0, 16, 64); pA0 += __shfl_xor(pA0, 32, 64);
    pA1 += __shfl_xor(pA1, 16, 64); pA1 += __shfl_xor(pA1, 32, 64);
    A0 = pA0; A1 = pA1;

    const float den  = task ? (0.235f * pA0 + 0.765f * pA1) : pA0;
    const float rden = __builtin_amdgcn_rcpf(den);
    const float rdh  = 0.5f * rden;
#pragma unroll
    for (int i = 0; i < 13; ++i) {
      const float num = task ? (0.235f * myv[i] + 0.765f * vtv[i]) : myv[i];
      Gt[i] = num * rden;    // Gt = w * G, init G = 1; 0 on pads
      wh[i] = num * rdh;     // 0.5 * psigma (damped-update coefficient)
      rc[i] = 1.0f;
    }
  }

  // ---- constant A fragments (k-permuted, row-remapped):
  //      afr[tp][kt][i] = S[row(16tp+s)][row(16*(2kt+(i>>2)) + 4g + (i&3))] ----
  bf16x8 afr[4][2];
#pragma unroll
  for (int tp = 0; tp < 4; ++tp)
#pragma unroll
    for (int kt = 0; kt < 2; ++kt) {
      bf16x8 v;
#pragma unroll
      for (int i = 0; i < 8; ++i) {
        const int kslot = 16 * (2 * kt + (i >> 2)) + 4 * g + (i & 3);
        v[i] = (bf16)sss_val(slot2row(16 * tp + s), slot2row(kslot));
      }
      afr[tp][kt] = v;
    }

  // tile-3 acc init: element 0 slot = 48+4g -> pad iff g==3 (+1 -> d=1).
  f32x4 pad3;
  pad3[0] = (g == 3) ? 1.0f : 0.0f;
  pad3[1] = pad3[2] = pad3[3] = 1.0f;

  f32x4 acc[4];

  // cvtb: Gt (13 f32) -> 7 packed dwords = the two bf16x8 B-fragments.
  auto matvec = [&]() {
    B8 x0, x1;
    x0.u[0] = cvt_pk(Gt[0],  Gt[1]);
    x0.u[1] = cvt_pk(Gt[2],  Gt[3]);
    x0.u[2] = cvt_pk(Gt[4],  Gt[5]);
    x0.u[3] = cvt_pk(Gt[6],  Gt[7]);
    x1.u[0] = cvt_pk(Gt[8],  Gt[9]);
    x1.u[1] = cvt_pk(Gt[10], Gt[11]);
    x1.u[2] = cvt_pk(Gt[12], 0.0f);
    x1.u[3] = 0;
    const bf16x8 b0 = x0.v, b1 = x1.v;

    const f32x4 z = {};
    __builtin_amdgcn_s_setprio(1);
#pragma unroll
    for (int tp = 0; tp < 3; ++tp) acc[tp] = mfma(afr[tp][0], b0, z);
    acc[3] = mfma(afr[3][0], b0, pad3);
#pragma unroll
    for (int tp = 0; tp < 4; ++tp) acc[tp] = mfma(afr[tp][1], b1, acc[tp]);
    __builtin_amdgcn_s_setprio(0);
  };

  auto upd_rcp = [&]() {
#pragma unroll
    for (int tp = 0; tp < 3; ++tp)
#pragma unroll
      for (int r = 0; r < 4; ++r) {
        const int i = 4 * tp + r;
        const float rcv = __builtin_amdgcn_rcpf(acc[tp][r]);
        rc[i] = rcv;
        Gt[i] = __builtin_fmaf(wh[i], rcv, 0.5f * Gt[i]);
      }
    {
      const float rcv = __builtin_amdgcn_rcpf(acc[3][0]);
      rc[12] = rcv;
      Gt[12] = __builtin_fmaf(wh[12], rcv, 0.5f * Gt[12]);
    }
  };

  auto upd_newton = [&]() {
#pragma unroll
    for (int tp = 0; tp < 3; ++tp)
#pragma unroll
      for (int r = 0; r < 4; ++r) {
        const int i = 4 * tp + r;
        const float nr  = __builtin_fmaf(-acc[tp][r], rc[i], 2.0f);
        const float rcv = rc[i] * nr;
        rc[i] = rcv;
        Gt[i] = __builtin_fmaf(wh[i], rcv, 0.5f * Gt[i]);
      }
    {
      const float nr  = __builtin_fmaf(-acc[3][0], rc[12], 2.0f);
      const float rcv = rc[12] * nr;
      rc[12] = rcv;
      Gt[12] = __builtin_fmaf(wh[12], rcv, 0.5f * Gt[12]);
    }
  };

  // ---- pipeline: d_0 in the prologue; update k consumes d_k, next matvec
  //      computes d_{k+1} ----
  matvec();
#pragma unroll 1
  for (int it = 0; it < KEXACT; ++it) { upd_rcp(); matvec(); }
#pragma unroll 1
  for (int it = KEXACT; it < NITERS - 1; ++it) { upd_newton(); matvec(); }
  upd_newton();   // final update (d_49) — no further matvec

  // ---- epilogue: S_task = sum_n psigma_pure[n] * ln(G[n]), G = Gt/w ----
  const float rA0 = __builtin_amdgcn_rcpf(A0);
  float Sp = 0.f;
#pragma unroll
  for (int t = 0; t < 4; ++t)
#pragma unroll
    for (int r = 0; r < 4; ++r) {
      const int li = 4 * t + r;
      if (li >= 13) continue;
      const int n = slot2row(16 * t + 4 * g + r);
      if (n < 51) {
        const float p  = (ein ? my_sigma[(size_t)ec * 51 + n] : 0.0f) * rA0;
        // guard w==0 (exact-0 input): p==0 there, force ln arg -> 1
        // G = Gt/w = Gt * rcp(2*wh) = Gt * 0.5 * rcp(wh)
        const float gg = (wh[li] != 0.0f)
                           ? Gt[li] * (0.5f * __builtin_amdgcn_rcpf(wh[li])) : 1.0f;
        Sp += p * __builtin_amdgcn_logf(gg);
      }
    }
  Sp += __shfl_xor(Sp, 16, 64);
  Sp += __shfl_xor(Sp, 32, 64);
  const float St = Sp * 0.69314718056f;
  const float So = __shfl_xor(St, 1, 64);   // partner task's sum

  if (task == 0 && g == 0 && ein) {
    const float lng_resid = A0 * (1.0f / 7.5f) * (So - St);
    const float v0  = v_comp[e];
    const float v1v = v_vt[e];
    const float q0 = A0 * (1.0f / 79.53f), q1 = A1 * (1.0f / 79.53f);
    const float r0 = v0 * (1.0f / 66.69f), r1 = v1v * (1.0f / 66.69f);
    const float xq = 0.235f * q0 + 0.765f * q1;
    const float xr = 0.235f * r0 + 0.765f * r1;
    const float theta = 0.235f * q0 * __builtin_amdgcn_rcpf(xq);
    const float phi   = 0.235f * r0 * __builtin_amdgcn_rcpf(xr);
    const float l0 = 5.0f * (r0 - q0) - (r0 - 1.0f);
    const float l1 = 5.0f * (r1 - q1) - (r1 - 1.0f);
    const float xl = 0.235f * l0 + 0.765f * l1;
    const float lng_comb = fast_log(phi * (1.0f / 0.235f))
                         + 5.0f * q0 * fast_log(theta * __builtin_amdgcn_rcpf(phi))
                         + l0 - (phi * (1.0f / 0.235f)) * xl;
    out[e] = lng_resid + lng_comb;
  }
}

extern "C" void kernel_launch(void* const* d_in, const int* in_sizes, int n_in,
                              void* d_out, int out_size, void* d_ws, size_t ws_size,
                              hipStream_t stream) {
  const float* my  = (const float*)d_in[0];
  const float* vc  = (const float*)d_in[1];
  const float* vts = (const float*)d_in[2];
  const float* vvt = (const float*)d_in[3];
  float* out = (float*)d_out;
  const int B = in_sizes[1];                    // v_compound is [B]
  const int grid = (B + 31) / 32;               // 32 elements per 256-thread block
  cosmo_mfma_r6<<<grid, 256, 0, stream>>>(my, vc, vts, vvt, out, B);
}

// Round 7
// 109.248 us; speedup vs baseline: 1.0026x; 1.0026x over previous
//
#include <hip/hip_runtime.h>

typedef __bf16 bf16;
typedef __attribute__((ext_vector_type(8))) bf16 bf16x8;
typedef __attribute__((ext_vector_type(4))) float f32x4;

namespace {

constexpr int NITERS = 50;   // R11 ERRATUM: ref's 50-iter iterate is NOT the
                             // fixed point; count must match exactly.
constexpr int KEXACT = 16;   // updates 0..15 use exact v_rcp (trans pipe);
                             // 16..49 use one Newton step.

// ---- compile-time physical constants (double) ----
constexpr double csqrt(double x) {
  double s = x > 1 ? x : 1;
  for (int i = 0; i < 60; ++i) s = 0.5 * (s + x / s);
  return s;
}
constexpr double AP_D =
    ((3.667 - 1.0) / (3.667 + 0.5)) * (0.3 * (7.5 * csqrt(7.5)) / 0.0002395);
constexpr double RGAST_D = (8.3144598 / 4184.0) * 623.15;

__device__ __forceinline__ float sss_val(int i, int j) {
  // SSS[i][j] = exp(-DELTAW/(RGAS*T)); symmetric; zero outside 51x51 (pad)
  if (i > 50 || j > 50) return 0.0f;
  const float si = -0.025f + 0.001f * (float)i;
  const float sj = -0.025f + 0.001f * (float)j;
  const float acc = fmaxf(0.0f, fmaxf(si, sj) - 0.0084f);
  const float don = fminf(0.0f, fminf(si, sj) + 0.0084f);
  const float dw = (float)(AP_D * 0.5) * (si + sj) * (si + sj) + 85580.0f * acc * don;
  return expf(-dw * (float)(1.0 / RGAST_D));
}

// Row-slot -> actual sigma-row. Slots 0..47 = rows 0..47. The 3 remaining
// real rows (48,49,50) live in tile-3 class r=0 (slots 48,52,56 = g 0..2);
// ALL of classes (tp=3, r>=1) are pad.
__device__ __forceinline__ int slot2row(int slot) {
  if (slot < 48) return slot;
  if ((slot & 3) == 0 && slot < 60) return 48 + ((slot - 48) >> 2);
  return 99;   // pad -> sss_val 0 / load 0
}

__device__ __forceinline__ float fast_log(float x) {
  return __builtin_amdgcn_logf(x) * 0.69314718056f;   // ln via log2
}

// HW-verified gfx950 shape (guide §3; R4/R5/R8/R9 passed with it).
__device__ __forceinline__ f32x4 mfma(bf16x8 a, bf16x8 b, f32x4 c) {
  return __builtin_amdgcn_mfma_f32_16x16x32_bf16(a, b, c, 0, 0, 0);
}

// Packed f32->bf16 (RNE, same rounding as the cast).
__device__ __forceinline__ unsigned cvt_pk(float lo, float hi) {
  unsigned r;
  asm("v_cvt_pk_bf16_f32 %0, %1, %2" : "=v"(r) : "v"(lo), "v"(hi));
  return r;
}

union B8 { unsigned u[4]; bf16x8 v; };

} // namespace

// One wave = ONE chain of 16 solves (8 elements x {pure,mix}); grid B/32,
// 4 waves/SIMD. R7: convoy de-phasing. The 4 waves co-resident on a SIMD
// come from 4 different blocks (n, n+256, n+512, n+768 under round-robin
// dispatch); phase-locked, they burst matvec together (matrix-pipe queue,
// then idle) and update together (VALU queue) -> every pipe ~25% duty,
// SIMD ~50% idle (R6 cycle accounting). A one-time stagger delay of
// ((blockIdx>>8)&3)*~192cyc spreads the 4 waves across the ~620-cyc matvec
// burst period. Zero semantic change.
__global__ __launch_bounds__(256, 4) void cosmo_mfma_r7(
    const float* __restrict__ my_sigma,   // [B,51]
    const float* __restrict__ v_comp,     // [B]
    const float* __restrict__ vt_sigma,   // [B,51,2]
    const float* __restrict__ v_vt,       // [B]
    float* __restrict__ out,              // [B]
    int B)
{
  // ---- convoy stagger: delay co-resident blocks by 0/1/2/3 x ~192 cyc ----
  {
    const int stag = (blockIdx.x >> 8) & 3;
#pragma unroll 1
    for (int i = 0; i < stag; ++i) __builtin_amdgcn_s_sleep(3);
  }

  const int lane = threadIdx.x & 63;
  const int wv   = threadIdx.x >> 6;
  const int s    = lane & 15;     // solve slot (C col / A-frag m pos)
  const int g    = lane >> 4;     // lane group 0..3
  const int task = s & 1;         // 0 = pure, 1 = mix
  const int e    = blockIdx.x * 32 + wv * 8 + (s >> 1);
  const bool ein = (e < B);
  const int  ec  = ein ? e : 0;

  // ---- prologue: rows owned by this lane (slot = 16t+4g+r) ----
  float A0, A1;
  float wh[13], Gt[13], rc[13];   // 12 live elements tiles 0-2, + 1 (tile3,r0)
  {
    float myv[13], vtv[13];
#pragma unroll
    for (int t = 0; t < 4; ++t)
#pragma unroll
      for (int r = 0; r < 4; ++r) {
        const int li = 4 * t + r;
        if (li >= 13) continue;                  // tile3 r>=1: dead
        const int n  = slot2row(16 * t + 4 * g + r);
        const bool nv = (n < 51) && ein;
        const int nc = (n < 51) ? n : 50;
        myv[li] = nv ? my_sigma[(size_t)ec * 51 + nc] : 0.0f;
        vtv[li] = nv ? vt_sigma[((size_t)ec * 51 + nc) * 2 + 1] : 0.0f;
      }
    float pA0 = 0.f, pA1 = 0.f;
#pragma unroll
    for (int i = 0; i < 13; ++i) { pA0 += myv[i]; pA1 += vtv[i]; }
    pA0 += __shfl_xor(pA0, 16, 64); pA0 += __shfl_xor(pA0, 32, 64);
    pA1 += __shfl_xor(pA1, 16, 64); pA1 += __shfl_xor(pA1, 32, 64);
    A0 = pA0; A1 = pA1;

    const float den  = task ? (0.235f * pA0 + 0.765f * pA1) : pA0;
    const float rden = __builtin_amdgcn_rcpf(den);
    const float rdh  = 0.5f * rden;
#pragma unroll
    for (int i = 0; i < 13; ++i) {
      const float num = task ? (0.235f * myv[i] + 0.765f * vtv[i]) : myv[i];
      Gt[i] = num * rden;    // Gt = w * G, init G = 1; 0 on pads
      wh[i] = num * rdh;     // 0.5 * psigma (damped-update coefficient)
      rc[i] = 1.0f;
    }
  }

  // ---- constant A fragments (k-permuted, row-remapped):
  //      afr[tp][kt][i] = S[row(16tp+s)][row(16*(2kt+(i>>2)) + 4g + (i&3))] ----
  bf16x8 afr[4][2];
#pragma unroll
  for (int tp = 0; tp < 4; ++tp)
#pragma unroll
    for (int kt = 0; kt < 2; ++kt) {
      bf16x8 v;
#pragma unroll
      for (int i = 0; i < 8; ++i) {
        const int kslot = 16 * (2 * kt + (i >> 2)) + 4 * g + (i & 3);
        v[i] = (bf16)sss_val(slot2row(16 * tp + s), slot2row(kslot));
      }
      afr[tp][kt] = v;
    }

  // tile-3 acc init: element 0 slot = 48+4g -> pad iff g==3 (+1 -> d=1).
  f32x4 pad3;
  pad3[0] = (g == 3) ? 1.0f : 0.0f;
  pad3[1] = pad3[2] = pad3[3] = 1.0f;

  f32x4 acc[4];

  // Gt (13 f32) -> 7 packed dwords = the two bf16x8 B-fragments; 8 MFMA.
  auto matvec = [&]() {
    B8 x0, x1;
    x0.u[0] = cvt_pk(Gt[0],  Gt[1]);
    x0.u[1] = cvt_pk(Gt[2],  Gt[3]);
    x0.u[2] = cvt_pk(Gt[4],  Gt[5]);
    x0.u[3] = cvt_pk(Gt[6],  Gt[7]);
    x1.u[0] = cvt_pk(Gt[8],  Gt[9]);
    x1.u[1] = cvt_pk(Gt[10], Gt[11]);
    x1.u[2] = cvt_pk(Gt[12], 0.0f);
    x1.u[3] = 0;
    const bf16x8 b0 = x0.v, b1 = x1.v;

    const f32x4 z = {};
#pragma unroll
    for (int tp = 0; tp < 3; ++tp) acc[tp] = mfma(afr[tp][0], b0, z);
    acc[3] = mfma(afr[3][0], b0, pad3);
#pragma unroll
    for (int tp = 0; tp < 4; ++tp) acc[tp] = mfma(afr[tp][1], b1, acc[tp]);
  };

  auto upd_rcp = [&]() {
#pragma unroll
    for (int tp = 0; tp < 3; ++tp)
#pragma unroll
      for (int r = 0; r < 4; ++r) {
        const int i = 4 * tp + r;
        const float rcv = __builtin_amdgcn_rcpf(acc[tp][r]);
        rc[i] = rcv;
        Gt[i] = __builtin_fmaf(wh[i], rcv, 0.5f * Gt[i]);
      }
    {
      const float rcv = __builtin_amdgcn_rcpf(acc[3][0]);
      rc[12] = rcv;
      Gt[12] = __builtin_fmaf(wh[12], rcv, 0.5f * Gt[12]);
    }
  };

  auto upd_newton = [&]() {
#pragma unroll
    for (int tp = 0; tp < 3; ++tp)
#pragma unroll
      for (int r = 0; r < 4; ++r) {
        const int i = 4 * tp + r;
        const float nr  = __builtin_fmaf(-acc[tp][r], rc[i], 2.0f);
        const float rcv = rc[i] * nr;
        rc[i] = rcv;
        Gt[i] = __builtin_fmaf(wh[i], rcv, 0.5f * Gt[i]);
      }
    {
      const float nr  = __builtin_fmaf(-acc[3][0], rc[12], 2.0f);
      const float rcv = rc[12] * nr;
      rc[12] = rcv;
      Gt[12] = __builtin_fmaf(wh[12], rcv, 0.5f * Gt[12]);
    }
  };

  // ---- pipeline: d_0 in the prologue; update k consumes d_k, next matvec
  //      computes d_{k+1} ----
  matvec();
#pragma unroll 1
  for (int it = 0; it < KEXACT; ++it) { upd_rcp(); matvec(); }
#pragma unroll 1
  for (int it = KEXACT; it < NITERS - 1; ++it) { upd_newton(); matvec(); }
  upd_newton();   // final update (d_49) — no further matvec

  // ---- epilogue: S_task = sum_n psigma_pure[n] * ln(G[n]), G = Gt/w ----
  const float rA0 = __builtin_amdgcn_rcpf(A0);
  float Sp = 0.f;
#pragma unroll
  for (int t = 0; t < 4; ++t)
#pragma unroll
    for (int r = 0; r < 4; ++r) {
      const int li = 4 * t + r;
      if (li >= 13) continue;
      const int n = slot2row(16 * t + 4 * g + r);
      if (n < 51) {
        const float p  = (ein ? my_sigma[(size_t)ec * 51 + n] : 0.0f) * rA0;
        // guard w==0 (exact-0 input): p==0 there, force ln arg -> 1
        // G = Gt/w = Gt * rcp(2*wh) = Gt * 0.5 * rcp(wh)
        const float gg = (wh[li] != 0.0f)
                           ? Gt[li] * (0.5f * __builtin_amdgcn_rcpf(wh[li])) : 1.0f;
        Sp += p * __builtin_amdgcn_logf(gg);
      }
    }
  Sp += __shfl_xor(Sp, 16, 64);
  Sp += __shfl_xor(Sp, 32, 64);
  const float St = Sp * 0.69314718056f;
  const float So = __shfl_xor(St, 1, 64);   // partner task's sum

  if (task == 0 && g == 0 && ein) {
    const float lng_resid = A0 * (1.0f / 7.5f) * (So - St);
    const float v0  = v_comp[e];
    const float v1v = v_vt[e];
    const float q0 = A0 * (1.0f / 79.53f), q1 = A1 * (1.0f / 79.53f);
    const float r0 = v0 * (1.0f / 66.69f), r1 = v1v * (1.0f / 66.69f);
    const float xq = 0.235f * q0 + 0.765f * q1;
    const float xr = 0.235f * r0 + 0.765f * r1;
    const float theta = 0.235f * q0 * __builtin_amdgcn_rcpf(xq);
    const float phi   = 0.235f * r0 * __builtin_amdgcn_rcpf(xr);
    const float l0 = 5.0f * (r0 - q0) - (r0 - 1.0f);
    const float l1 = 5.0f * (r1 - q1) - (r1 - 1.0f);
    const float xl = 0.235f * l0 + 0.765f * l1;
    const float lng_comb = fast_log(phi * (1.0f / 0.235f))
                         + 5.0f * q0 * fast_log(theta * __builtin_amdgcn_rcpf(phi))
                         + l0 - (phi * (1.0f / 0.235f)) * xl;
    out[e] = lng_resid + lng_comb;
  }
}

extern "C" void kernel_launch(void* const* d_in, const int* in_sizes, int n_in,
                              void* d_out, int out_size, void* d_ws, size_t ws_size,
                              hipStream_t stream) {
  const float* my  = (const float*)d_in[0];
  const float* vc  = (const float*)d_in[1];
  const float* vts = (const float*)d_in[2];
  const float* vvt = (const float*)d_in[3];
  float* out = (float*)d_out;
  const int B = in_sizes[1];                    // v_compound is [B]
  const int grid = (B + 31) / 32;               // 32 elements per 256-thread block
  cosmo_mfma_r7<<<grid, 256, 0, stream>>>(my, vc, vts, vvt, out, B);
}